// Round 5
// baseline (1838.714 us; speedup 1.0000x reference)
//
#include <hip/hip_runtime.h>
#include <hip/hip_bf16.h>
#include <cmath>

#define T_STEPS 50
#define BATCH   8192
#define ROWS    32                 // rows per block
#define NBLK    (BATCH / ROWS)     // 256 blocks
#define THREADS 1024               // 16 waves; one N-tile (16 cols) per wave

typedef float  f32x4  __attribute__((ext_vector_type(4)));
typedef __bf16 bf16x8 __attribute__((ext_vector_type(8)));

// ---- packed weight regions in d_ws (bf16), all padded to 16 N-tiles ----
// B-frag layout: [ntile][kstep][lane(64)][8]; n = nt*16 + (lane&15), k = ks*32 + (lane>>4)*8 + e
#define N_FC   (16*2*512)
#define N_R    (16*14*512)
#define N_Z    (16*14*512)
#define N_IN   (16*7*512)
#define N_HN   (16*7*512)
#define N_W1   (16*7*512)
#define N_MV   (4*7*512)
#define OFF_FC 0
#define OFF_R  (OFF_FC + N_FC)     // 16384
#define OFF_Z  (OFF_R  + N_R)      // 131072
#define OFF_IN (OFF_Z  + N_Z)      // 245760
#define OFF_HN (OFF_IN + N_IN)     // 303104
#define OFF_W1 (OFF_HN + N_HN)     // 360448
#define OFF_MV (OFF_W1 + N_W1)     // 417792
#define W_TOTAL (OFF_MV + N_MV)    // 432128 elems = 864 KB

__device__ __forceinline__ unsigned short f2b(float f) {
    union { float f; unsigned u; } v; v.f = f;
    unsigned r = v.u + 0x7FFFu + ((v.u >> 16) & 1u);
    return (unsigned short)(r >> 16);
}
__device__ __forceinline__ float b2f(unsigned short h) {
    union { unsigned u; float f; } v; v.u = ((unsigned)h) << 16;
    return v.f;
}
__device__ __forceinline__ int fragSlot(int row, int k) {
    int sub = k & 31;
    return ((((sub >> 3) & 3) << 4) | row) * 8 + (sub & 7);
}
__device__ __forceinline__ f32x4 MFMA(bf16x8 a, bf16x8 b, f32x4 c) {
    return __builtin_amdgcn_mfma_f32_16x16x32_bf16(a, b, c, 0, 0, 0);
}
__device__ __forceinline__ float sigmf(float x) { return 1.f / (1.f + __expf(-x)); }
__device__ __forceinline__ float tanh_fast(float x) {
    float e = __expf(2.f * fminf(x, 40.f));
    return (e - 1.f) / (e + 1.f);
}
__device__ __forceinline__ void st_nt4(float* p, f32x4 v) {
    __builtin_nontemporal_store(v, reinterpret_cast<f32x4*>(p));
}
__device__ __forceinline__ float ld_nt(const float* p) { return __builtin_nontemporal_load(p); }

// ================= weight prep: fp32 -> bf16, padded to 16 tiles, fragment-ordered =================
__global__ void rssm_prep(const float* __restrict__ Wfc, const float* __restrict__ Wih,
                          const float* __restrict__ Whh, const float* __restrict__ W1,
                          const float* __restrict__ Wmu, const float* __restrict__ Wvar,
                          unsigned short* __restrict__ out)
{
    int idx = blockIdx.x * 256 + threadIdx.x;
    if (idx >= W_TOTAL) return;
    float v = 0.f;
    if (idx < OFF_R) {                        // FC: [16][2][512], W_fc [200,36]
        int loc = idx - OFF_FC;
        int nt = loc / (2 * 512), r = loc % (2 * 512), ks = r / 512, li = r % 512;
        int lane = li >> 3, e = li & 7;
        int n = nt * 16 + (lane & 15);
        int k = ks * 32 + (lane >> 4) * 8 + e;
        if (n < 200 && k < 36) v = Wfc[n * 36 + k];
    } else if (idx < OFF_Z) {                 // R gate: K = x(0..223)|h(224..447)
        int loc = idx - OFF_R;
        int nt = loc / (14 * 512), r = loc % (14 * 512), ks = r / 512, li = r % 512;
        int lane = li >> 3, e = li & 7;
        int n = nt * 16 + (lane & 15);
        int k = ks * 32 + (lane >> 4) * 8 + e;
        if (n < 200) {
            if (k < 224) { if (k < 200) v = Wih[n * 200 + k]; }
            else { int kk = k - 224; if (kk < 200) v = Whh[n * 200 + kk]; }
        }
    } else if (idx < OFF_IN) {                // Z gate
        int loc = idx - OFF_Z;
        int nt = loc / (14 * 512), r = loc % (14 * 512), ks = r / 512, li = r % 512;
        int lane = li >> 3, e = li & 7;
        int n = nt * 16 + (lane & 15);
        int k = ks * 32 + (lane >> 4) * 8 + e;
        if (n < 200) {
            if (k < 224) { if (k < 200) v = Wih[(200 + n) * 200 + k]; }
            else { int kk = k - 224; if (kk < 200) v = Whh[(200 + n) * 200 + kk]; }
        }
    } else if (idx < OFF_HN) {                // IN: n-gate of W_ih
        int loc = idx - OFF_IN;
        int nt = loc / (7 * 512), r = loc % (7 * 512), ks = r / 512, li = r % 512;
        int lane = li >> 3, e = li & 7;
        int n = nt * 16 + (lane & 15);
        int k = ks * 32 + (lane >> 4) * 8 + e;
        if (n < 200 && k < 200) v = Wih[(400 + n) * 200 + k];
    } else if (idx < OFF_W1) {                // HN: n-gate of W_hh
        int loc = idx - OFF_HN;
        int nt = loc / (7 * 512), r = loc % (7 * 512), ks = r / 512, li = r % 512;
        int lane = li >> 3, e = li & 7;
        int n = nt * 16 + (lane & 15);
        int k = ks * 32 + (lane >> 4) * 8 + e;
        if (n < 200 && k < 200) v = Whh[(400 + n) * 200 + k];
    } else if (idx < OFF_MV) {                // W1
        int loc = idx - OFF_W1;
        int nt = loc / (7 * 512), r = loc % (7 * 512), ks = r / 512, li = r % 512;
        int lane = li >> 3, e = li & 7;
        int n = nt * 16 + (lane & 15);
        int k = ks * 32 + (lane >> 4) * 8 + e;
        if (n < 200 && k < 200) v = W1[n * 200 + k];
    } else {                                  // MV: nt 0-1 mu rows, nt 2-3 var rows
        int loc = idx - OFF_MV;
        int nt = loc / (7 * 512), r = loc % (7 * 512), ks = r / 512, li = r % 512;
        int lane = li >> 3, e = li & 7;
        int k = ks * 32 + (lane >> 4) * 8 + e;
        if (nt < 2) { int m = nt * 16 + (lane & 15); if (m < 30 && k < 200) v = Wmu[m * 200 + k]; }
        else        { int m = (nt - 2) * 16 + (lane & 15); if (m < 30 && k < 200) v = Wvar[m * 200 + k]; }
    }
    out[idx] = f2b(v);
}

// ================= main kernel: 256 blocks x 32 rows, 16 waves (1 N-tile each) =================
__global__ __launch_bounds__(THREADS, 4) void rssm_main(
    const float* __restrict__ actions, const float* __restrict__ h0,
    const float* __restrict__ s0, const float* __restrict__ noise,
    const float* __restrict__ b_fc, const float* __restrict__ b_ih,
    const float* __restrict__ b_hh, const float* __restrict__ b1,
    const float* __restrict__ bmu, const float* __restrict__ bvar,
    const unsigned short* __restrict__ W, float* __restrict__ out)
{
    // Activation buffers, MFMA A-fragment layout [mt][ks][512] (mt in 0..1)
    __shared__ __align__(16) unsigned short Xb[2 * 7 * 512];        // x, k 0..223    (14336 B)
    __shared__ __align__(16) unsigned short Hb[2 * 2 * 7 * 512];    // h ping-pong    (28672 B)
    __shared__ __align__(16) unsigned short HIDb[2 * 7 * 512];      // hidden         (14336 B)
    __shared__ __align__(16) unsigned short SAb[2 * 2 * 512];       // s|a, k 0..35   (4096 B)
    __shared__ __align__(16) float STG_S[ROWS * 200];               // states stage   (25600 B)
    __shared__ __align__(16) float STG_Z[2][ROWS * 30];             // stoch stage x2 (7680 B)

    const int tid = threadIdx.x;
    const int w = tid >> 6, lane = tid & 63;
    const int col = lane & 15, kg = lane >> 4;
    const int brow0 = blockIdx.x * ROWS;
    const int jt = w;                          // one 16-col N-tile per wave (tiles 13..15 are pad)
    const int j = jt * 16 + col;
    const bool jv = (j < 200);

    const unsigned short* WFC = W + OFF_FC;
    const unsigned short* WRr = W + OFF_R;
    const unsigned short* WZr = W + OFF_Z;
    const unsigned short* WIN = W + OFF_IN;
    const unsigned short* WHN = W + OFF_HN;
    const unsigned short* W1w = W + OFF_W1;
    const unsigned short* WMV = W + OFF_MV;
    float* out_states = out;
    float* out_stoch  = out + (size_t)T_STEPS * BATCH * 200;

    // ---- hoisted per-thread biases ----
    float bfcv = 0.f, brv = 0.f, bzv = 0.f, biv = 0.f, bhv = 0.f, b1v = 0.f;
    if (jv) {
        bfcv = b_fc[j];
        brv = b_ih[j] + b_hh[j];
        bzv = b_ih[200 + j] + b_hh[200 + j];
        biv = b_ih[400 + j];
        bhv = b_hh[400 + j];
        b1v = b1[j];
    }
    float bmuv = 0.f, bvav = 0.f;
    if (w < 4) {
        const int jm = (w & 1) * 16 + col;
        if (jm < 30) { bmuv = bmu[jm]; bvav = bvar[jm]; }
    }

    // ---- init: zero LDS (pad slots must be 0), load h0/s0/a0 ----
    for (int i = tid; i < 2 * 7 * 512;     i += THREADS) Xb[i] = 0;
    for (int i = tid; i < 2 * 2 * 7 * 512; i += THREADS) Hb[i] = 0;
    for (int i = tid; i < 2 * 7 * 512;     i += THREADS) HIDb[i] = 0;
    for (int i = tid; i < 2 * 2 * 512;     i += THREADS) SAb[i] = 0;
    __syncthreads();
    for (int i = tid; i < ROWS * 200; i += THREADS) {
        int r = i / 200, jj = i % 200;
        Hb[((0 * 2 + (r >> 4)) * 7 + (jj >> 5)) * 512 + fragSlot(r & 15, jj)] =
            f2b(h0[(size_t)(brow0 + r) * 200 + jj]);
    }
    for (int i = tid; i < ROWS * 30; i += THREADS) {
        int r = i / 30, jj = i % 30;
        SAb[((r >> 4) * 2) * 512 + fragSlot(r & 15, jj)] =
            f2b(s0[(size_t)(brow0 + r) * 30 + jj]);
    }
    for (int i = tid; i < ROWS * 6; i += THREADS) {
        int r = i / 6, c = i % 6, k = 30 + c;
        SAb[((r >> 4) * 2 + (k >> 5)) * 512 + fragSlot(r & 15, k)] =
            f2b(ld_nt(&actions[(size_t)(brow0 + r) * 6 + c]));
    }
    __syncthreads();

    for (int t = 0; t < T_STEPS; ++t) {
        const int cur = t & 1, nxt = cur ^ 1;

        // ---------- Phase 1: x = FC(concat(s,a)) -> Xb ----------
        {
            f32x4 c0 = {0.f,0.f,0.f,0.f}, c1 = {0.f,0.f,0.f,0.f};
            #pragma unroll
            for (int ks = 0; ks < 2; ++ks) {
                bf16x8 b  = *reinterpret_cast<const bf16x8*>(&WFC[(size_t)(jt * 2 + ks) * 512 + lane * 8]);
                bf16x8 a0 = *reinterpret_cast<const bf16x8*>(&SAb[(0 * 2 + ks) * 512 + lane * 8]);
                bf16x8 a1 = *reinterpret_cast<const bf16x8*>(&SAb[(1 * 2 + ks) * 512 + lane * 8]);
                c0 = MFMA(a0, b, c0);
                c1 = MFMA(a1, b, c1);
            }
            if (jt < 14) {     // x has k-slots 0..223 only; pad tiles produce zeros anyway
                #pragma unroll
                for (int q = 0; q < 4; ++q) {
                    Xb[(0 * 7 + (j >> 5)) * 512 + fragSlot(kg * 4 + q, j)] = f2b(c0[q] + bfcv);
                    Xb[(1 * 7 + (j >> 5)) * 512 + fragSlot(kg * 4 + q, j)] = f2b(c1[q] + bfcv);
                }
            }
        }
        __syncthreads();

        // ---------- Phase 2: gate GEMMs (R,Z over [x|h]; Ni over x, Nh over h) + elementwise ----------
        {
            f32x4 aR[2], aZ[2], aNi[2], aNh[2];
            #pragma unroll
            for (int mt = 0; mt < 2; ++mt) {
                aR[mt] = (f32x4){0.f,0.f,0.f,0.f}; aZ[mt] = (f32x4){0.f,0.f,0.f,0.f};
                aNi[mt] = (f32x4){0.f,0.f,0.f,0.f}; aNh[mt] = (f32x4){0.f,0.f,0.f,0.f};
            }
            #pragma unroll
            for (int ks = 0; ks < 14; ++ks) {
                bf16x8 bR = *reinterpret_cast<const bf16x8*>(&WRr[(size_t)(jt * 14 + ks) * 512 + lane * 8]);
                bf16x8 bZ = *reinterpret_cast<const bf16x8*>(&WZr[(size_t)(jt * 14 + ks) * 512 + lane * 8]);
                bf16x8 bN = (ks < 7)
                    ? *reinterpret_cast<const bf16x8*>(&WIN[(size_t)(jt * 7 + ks) * 512 + lane * 8])
                    : *reinterpret_cast<const bf16x8*>(&WHN[(size_t)(jt * 7 + (ks - 7)) * 512 + lane * 8]);
                #pragma unroll
                for (int mt = 0; mt < 2; ++mt) {
                    bf16x8 a = (ks < 7)
                        ? *reinterpret_cast<const bf16x8*>(&Xb[(mt * 7 + ks) * 512 + lane * 8])
                        : *reinterpret_cast<const bf16x8*>(&Hb[((cur * 2 + mt) * 7 + (ks - 7)) * 512 + lane * 8]);
                    aR[mt] = MFMA(a, bR, aR[mt]);
                    aZ[mt] = MFMA(a, bZ, aZ[mt]);
                    if (ks < 7) aNi[mt] = MFMA(a, bN, aNi[mt]);
                    else        aNh[mt] = MFMA(a, bN, aNh[mt]);
                }
            }
            #pragma unroll
            for (int mt = 0; mt < 2; ++mt) {
                #pragma unroll
                for (int q = 0; q < 4; ++q) {
                    const int r0 = kg * 4 + q;
                    const int slot = (j >> 5) * 512 + fragSlot(r0, j);
                    float rg = sigmf(aR[mt][q] + brv);
                    float zg = sigmf(aZ[mt][q] + bzv);
                    float ng = tanh_fast((aNi[mt][q] + biv) + rg * (aNh[mt][q] + bhv));
                    if (jv) {
                        float hv = b2f(Hb[(cur * 2 + mt) * 7 * 512 + slot]);
                        float hn = (1.f - zg) * ng + zg * hv;
                        Hb[(nxt * 2 + mt) * 7 * 512 + slot] = f2b(hn);
                        STG_S[(mt * 16 + r0) * 200 + j] = hn;
                    }
                }
            }
        }
        __syncthreads();

        // ---------- Phase 3: hid = relu(h_new @ W1^T + b1) -> HIDb ----------
        {
            f32x4 c0 = {0.f,0.f,0.f,0.f}, c1 = {0.f,0.f,0.f,0.f};
            #pragma unroll
            for (int ks = 0; ks < 7; ++ks) {
                bf16x8 b  = *reinterpret_cast<const bf16x8*>(&W1w[(size_t)(jt * 7 + ks) * 512 + lane * 8]);
                bf16x8 a0 = *reinterpret_cast<const bf16x8*>(&Hb[((nxt * 2 + 0) * 7 + ks) * 512 + lane * 8]);
                bf16x8 a1 = *reinterpret_cast<const bf16x8*>(&Hb[((nxt * 2 + 1) * 7 + ks) * 512 + lane * 8]);
                c0 = MFMA(a0, b, c0);
                c1 = MFMA(a1, b, c1);
            }
            if (jt < 14) {
                #pragma unroll
                for (int q = 0; q < 4; ++q) {
                    HIDb[(0 * 7 + (j >> 5)) * 512 + fragSlot(kg * 4 + q, j)] = f2b(fmaxf(c0[q] + b1v, 0.f));
                    HIDb[(1 * 7 + (j >> 5)) * 512 + fragSlot(kg * 4 + q, j)] = f2b(fmaxf(c1[q] + b1v, 0.f));
                }
            }
        }
        __syncthreads();

        // ---------- Phase 4: waves 0-3 mu/var -> s_new ; waves 4-15 drain outputs + prefetch a ----------
        if (w < 4) {
            const int mt = w >> 1, ntile = w & 1;
            f32x4 cm = {0.f,0.f,0.f,0.f}, cv = {0.f,0.f,0.f,0.f};
            #pragma unroll
            for (int ks = 0; ks < 7; ++ks) {
                bf16x8 a  = *reinterpret_cast<const bf16x8*>(&HIDb[(mt * 7 + ks) * 512 + lane * 8]);
                bf16x8 bm = *reinterpret_cast<const bf16x8*>(&WMV[(size_t)(ntile * 7 + ks) * 512 + lane * 8]);
                bf16x8 bv = *reinterpret_cast<const bf16x8*>(&WMV[(size_t)((2 + ntile) * 7 + ks) * 512 + lane * 8]);
                cm = MFMA(a, bm, cm);
                cv = MFMA(a, bv, cv);
            }
            const int jm = ntile * 16 + col;
            const bool jmv = (jm < 30);
            #pragma unroll
            for (int q = 0; q < 4; ++q) {
                const int r0 = kg * 4 + q;
                const int row = mt * 16 + r0;
                float mu = cm[q] + bmuv;
                float vr = cv[q] + bvav;
                float var = ((vr > 20.f) ? vr : log1pf(__expf(vr))) + 0.1f;
                if (jmv) {
                    float eps = ld_nt(&noise[((size_t)t * BATCH + brow0 + row) * 30 + jm]);
                    float sn = mu + var * eps;
                    STG_Z[t & 1][row * 30 + jm] = sn;
                    SAb[(mt * 2) * 512 + fragSlot(r0, jm)] = f2b(sn);
                }
            }
        } else {
            const int di = (w - 4) * 64 + lane;   // 0..767
            // drain states(t): 1600 float4, full-line nt stores
            float* dst = out_states + ((size_t)t * BATCH + brow0) * 200;
            for (int i = di; i < 1600; i += 768) {
                f32x4 v = *reinterpret_cast<const f32x4*>(&STG_S[i * 4]);
                st_nt4(dst + i * 4, v);
            }
            // drain stoch(t-1): 240 float4
            if (t >= 1 && di < 240) {
                f32x4 v = *reinterpret_cast<const f32x4*>(&STG_Z[(t - 1) & 1][di * 4]);
                st_nt4(out_stoch + ((size_t)(t - 1) * BATCH + brow0) * 30 + di * 4, v);
            }
            // prefetch actions(t+1)
            if (t + 1 < T_STEPS && di < ROWS * 6) {
                const int r = di / 6, c = di % 6, k = 30 + c;
                float av = ld_nt(&actions[((size_t)(t + 1) * BATCH + brow0 + r) * 6 + c]);
                SAb[((r >> 4) * 2 + (k >> 5)) * 512 + fragSlot(r & 15, k)] = f2b(av);
            }
        }
        __syncthreads();
    }

    // drain stoch(T-1)
    if (tid < 240) {
        f32x4 v = *reinterpret_cast<const f32x4*>(&STG_Z[(T_STEPS - 1) & 1][tid * 4]);
        st_nt4(out_stoch + ((size_t)(T_STEPS - 1) * BATCH + brow0) * 30 + tid * 4, v);
    }
}

extern "C" void kernel_launch(void* const* d_in, const int* in_sizes, int n_in,
                              void* d_out, int out_size, void* d_ws, size_t ws_size,
                              hipStream_t stream)
{
    const float* actions = (const float*)d_in[0];
    const float* h0      = (const float*)d_in[1];
    const float* s0      = (const float*)d_in[2];
    const float* noise   = (const float*)d_in[3];
    const float* Wfc     = (const float*)d_in[4];
    const float* bfc     = (const float*)d_in[5];
    const float* Wih     = (const float*)d_in[6];
    const float* bih     = (const float*)d_in[7];
    const float* Whh     = (const float*)d_in[8];
    const float* bhh     = (const float*)d_in[9];
    const float* W1      = (const float*)d_in[10];
    const float* b1      = (const float*)d_in[11];
    const float* Wmu     = (const float*)d_in[12];
    const float* bmu     = (const float*)d_in[13];
    const float* Wvar    = (const float*)d_in[14];
    const float* bvar    = (const float*)d_in[15];

    unsigned short* wbuf = (unsigned short*)d_ws;

    rssm_prep<<<(W_TOTAL + 255) / 256, 256, 0, stream>>>(Wfc, Wih, Whh, W1, Wmu, Wvar, wbuf);
    rssm_main<<<NBLK, THREADS, 0, stream>>>(actions, h0, s0, noise, bfc, bih, bhh, b1,
                                            bmu, bvar, wbuf, (float*)d_out);
}

// Round 6
// 1757.944 us; speedup vs baseline: 1.0459x; 1.0459x over previous
//
#include <hip/hip_runtime.h>
#include <hip/hip_bf16.h>
#include <cmath>

#define T_STEPS 50
#define BATCH   8192
#define ROWS    32                 // rows per block
#define NBLK    (BATCH / ROWS)     // 256 blocks
#define THREADS 1024               // 16 waves; one N-tile (16 cols) per wave

typedef float  f32x4  __attribute__((ext_vector_type(4)));
typedef __bf16 bf16x8 __attribute__((ext_vector_type(8)));

// ---- packed weight regions in d_ws (bf16), all padded to 16 N-tiles ----
// B-frag layout: [ntile][kstep][lane(64)][8]; n = nt*16 + (lane&15), k = ks*32 + (lane>>4)*8 + e
#define N_FC   (16*2*512)
#define N_R    (16*14*512)
#define N_Z    (16*14*512)
#define N_IN   (16*7*512)
#define N_HN   (16*7*512)
#define N_W1   (16*7*512)
#define N_MV   (4*7*512)
#define OFF_FC 0
#define OFF_R  (OFF_FC + N_FC)
#define OFF_Z  (OFF_R  + N_R)
#define OFF_IN (OFF_Z  + N_Z)
#define OFF_HN (OFF_IN + N_IN)
#define OFF_W1 (OFF_HN + N_HN)
#define OFF_MV (OFF_W1 + N_W1)
#define W_TOTAL (OFF_MV + N_MV)    // 432128 elems = 864 KB

__device__ __forceinline__ unsigned short f2b(float f) {
    union { float f; unsigned u; } v; v.f = f;
    unsigned r = v.u + 0x7FFFu + ((v.u >> 16) & 1u);
    return (unsigned short)(r >> 16);
}
__device__ __forceinline__ float b2f(unsigned short h) {
    union { unsigned u; float f; } v; v.u = ((unsigned)h) << 16;
    return v.f;
}
__device__ __forceinline__ int fragSlot(int row, int k) {
    int sub = k & 31;
    return ((((sub >> 3) & 3) << 4) | row) * 8 + (sub & 7);
}
__device__ __forceinline__ f32x4 MFMA(bf16x8 a, bf16x8 b, f32x4 c) {
    return __builtin_amdgcn_mfma_f32_16x16x32_bf16(a, b, c, 0, 0, 0);
}
__device__ __forceinline__ float sigmf(float x) { return 1.f / (1.f + __expf(-x)); }
__device__ __forceinline__ float tanh_fast(float x) {
    float e = __expf(2.f * fminf(x, 40.f));
    return (e - 1.f) / (e + 1.f);
}
__device__ __forceinline__ void st_nt4(float* p, f32x4 v) {
    __builtin_nontemporal_store(v, reinterpret_cast<f32x4*>(p));
}
__device__ __forceinline__ float ld_nt(const float* p) { return __builtin_nontemporal_load(p); }

// ================= weight prep: fp32 -> bf16, padded to 16 tiles, fragment-ordered =================
__global__ void rssm_prep(const float* __restrict__ Wfc, const float* __restrict__ Wih,
                          const float* __restrict__ Whh, const float* __restrict__ W1,
                          const float* __restrict__ Wmu, const float* __restrict__ Wvar,
                          unsigned short* __restrict__ out)
{
    int idx = blockIdx.x * 256 + threadIdx.x;
    if (idx >= W_TOTAL) return;
    float v = 0.f;
    if (idx < OFF_R) {                        // FC: [16][2][512], W_fc [200,36]
        int loc = idx - OFF_FC;
        int nt = loc / (2 * 512), r = loc % (2 * 512), ks = r / 512, li = r % 512;
        int lane = li >> 3, e = li & 7;
        int n = nt * 16 + (lane & 15);
        int k = ks * 32 + (lane >> 4) * 8 + e;
        if (n < 200 && k < 36) v = Wfc[n * 36 + k];
    } else if (idx < OFF_Z) {                 // R gate: K = x(0..223)|h(224..447)
        int loc = idx - OFF_R;
        int nt = loc / (14 * 512), r = loc % (14 * 512), ks = r / 512, li = r % 512;
        int lane = li >> 3, e = li & 7;
        int n = nt * 16 + (lane & 15);
        int k = ks * 32 + (lane >> 4) * 8 + e;
        if (n < 200) {
            if (k < 224) { if (k < 200) v = Wih[n * 200 + k]; }
            else { int kk = k - 224; if (kk < 200) v = Whh[n * 200 + kk]; }
        }
    } else if (idx < OFF_IN) {                // Z gate
        int loc = idx - OFF_Z;
        int nt = loc / (14 * 512), r = loc % (14 * 512), ks = r / 512, li = r % 512;
        int lane = li >> 3, e = li & 7;
        int n = nt * 16 + (lane & 15);
        int k = ks * 32 + (lane >> 4) * 8 + e;
        if (n < 200) {
            if (k < 224) { if (k < 200) v = Wih[(200 + n) * 200 + k]; }
            else { int kk = k - 224; if (kk < 200) v = Whh[(200 + n) * 200 + kk]; }
        }
    } else if (idx < OFF_HN) {                // IN: n-gate of W_ih
        int loc = idx - OFF_IN;
        int nt = loc / (7 * 512), r = loc % (7 * 512), ks = r / 512, li = r % 512;
        int lane = li >> 3, e = li & 7;
        int n = nt * 16 + (lane & 15);
        int k = ks * 32 + (lane >> 4) * 8 + e;
        if (n < 200 && k < 200) v = Wih[(400 + n) * 200 + k];
    } else if (idx < OFF_W1) {                // HN: n-gate of W_hh
        int loc = idx - OFF_HN;
        int nt = loc / (7 * 512), r = loc % (7 * 512), ks = r / 512, li = r % 512;
        int lane = li >> 3, e = li & 7;
        int n = nt * 16 + (lane & 15);
        int k = ks * 32 + (lane >> 4) * 8 + e;
        if (n < 200 && k < 200) v = Whh[(400 + n) * 200 + k];
    } else if (idx < OFF_MV) {                // W1
        int loc = idx - OFF_W1;
        int nt = loc / (7 * 512), r = loc % (7 * 512), ks = r / 512, li = r % 512;
        int lane = li >> 3, e = li & 7;
        int n = nt * 16 + (lane & 15);
        int k = ks * 32 + (lane >> 4) * 8 + e;
        if (n < 200 && k < 200) v = W1[n * 200 + k];
    } else {                                  // MV: nt 0-1 mu rows, nt 2-3 var rows
        int loc = idx - OFF_MV;
        int nt = loc / (7 * 512), r = loc % (7 * 512), ks = r / 512, li = r % 512;
        int lane = li >> 3, e = li & 7;
        int k = ks * 32 + (lane >> 4) * 8 + e;
        if (nt < 2) { int m = nt * 16 + (lane & 15); if (m < 30 && k < 200) v = Wmu[m * 200 + k]; }
        else        { int m = (nt - 2) * 16 + (lane & 15); if (m < 30 && k < 200) v = Wvar[m * 200 + k]; }
    }
    out[idx] = f2b(v);
}

// ================= main kernel: 256 blocks x 32 rows, 16 waves, weights register-resident =================
__global__ __launch_bounds__(THREADS, 4) void rssm_main(
    const float* __restrict__ actions, const float* __restrict__ h0,
    const float* __restrict__ s0, const float* __restrict__ noise,
    const float* __restrict__ b_fc, const float* __restrict__ b_ih,
    const float* __restrict__ b_hh, const float* __restrict__ b1,
    const float* __restrict__ bmu, const float* __restrict__ bvar,
    const unsigned short* __restrict__ W, float* __restrict__ out)
{
    // Activation buffers, MFMA A-fragment layout [mt][ks][512] (mt in 0..1)
    __shared__ __align__(16) unsigned short Xb[2 * 7 * 512];        // x, k 0..223
    __shared__ __align__(16) unsigned short Hb[2 * 2 * 7 * 512];    // h ping-pong
    __shared__ __align__(16) unsigned short HIDb[2 * 7 * 512];      // hidden
    __shared__ __align__(16) unsigned short SAb[2 * 2 * 512];       // s|a, k 0..35
    __shared__ __align__(16) float STG_S[ROWS * 200];               // states stage
    __shared__ __align__(16) float STG_Z[2][ROWS * 30];             // stoch stage x2

    const int tid = threadIdx.x;
    const int w = tid >> 6, lane = tid & 63;
    const int col = lane & 15, kg = lane >> 4;
    const int brow0 = blockIdx.x * ROWS;
    const int jt = w;                          // one 16-col N-tile per wave (13..15 pad)
    const int j = jt * 16 + col;
    const bool jv = (j < 200);

    const unsigned short* WFC = W + OFF_FC;
    const unsigned short* WRr = W + OFF_R;
    const unsigned short* WZr = W + OFF_Z;
    const unsigned short* WIN = W + OFF_IN;
    const unsigned short* WHN = W + OFF_HN;
    const unsigned short* W1w = W + OFF_W1;
    const unsigned short* WMV = W + OFF_MV;
    float* out_states = out;
    float* out_stoch  = out + (size_t)T_STEPS * BATCH * 200;

    // ---- persistent per-wave weight fragments (register-resident across all 50 steps) ----
    bf16x8 wFC[2], wR[14], wZ[14], wN[14], wW1[7];   // wN: [0..6]=Ni, [7..13]=Nh
    #pragma unroll
    for (int ks = 0; ks < 2; ++ks)
        wFC[ks] = *reinterpret_cast<const bf16x8*>(&WFC[(size_t)(jt * 2 + ks) * 512 + lane * 8]);
    #pragma unroll
    for (int ks = 0; ks < 14; ++ks)
        wR[ks] = *reinterpret_cast<const bf16x8*>(&WRr[(size_t)(jt * 14 + ks) * 512 + lane * 8]);
    #pragma unroll
    for (int ks = 0; ks < 14; ++ks)
        wZ[ks] = *reinterpret_cast<const bf16x8*>(&WZr[(size_t)(jt * 14 + ks) * 512 + lane * 8]);
    #pragma unroll
    for (int ks = 0; ks < 7; ++ks)
        wN[ks] = *reinterpret_cast<const bf16x8*>(&WIN[(size_t)(jt * 7 + ks) * 512 + lane * 8]);
    #pragma unroll
    for (int ks = 0; ks < 7; ++ks)
        wN[7 + ks] = *reinterpret_cast<const bf16x8*>(&WHN[(size_t)(jt * 7 + ks) * 512 + lane * 8]);
    #pragma unroll
    for (int ks = 0; ks < 7; ++ks)
        wW1[ks] = *reinterpret_cast<const bf16x8*>(&W1w[(size_t)(jt * 7 + ks) * 512 + lane * 8]);
    bf16x8 wM[7], wV[7];                              // only waves 0-3 use these
    if (w < 4) {
        const int ntile = w & 1;
        #pragma unroll
        for (int ks = 0; ks < 7; ++ks) {
            wM[ks] = *reinterpret_cast<const bf16x8*>(&WMV[(size_t)(ntile * 7 + ks) * 512 + lane * 8]);
            wV[ks] = *reinterpret_cast<const bf16x8*>(&WMV[(size_t)((2 + ntile) * 7 + ks) * 512 + lane * 8]);
        }
    }

    // ---- hoisted per-thread biases ----
    float bfcv = 0.f, brv = 0.f, bzv = 0.f, biv = 0.f, bhv = 0.f, b1v = 0.f;
    if (jv) {
        bfcv = b_fc[j];
        brv = b_ih[j] + b_hh[j];
        bzv = b_ih[200 + j] + b_hh[200 + j];
        biv = b_ih[400 + j];
        bhv = b_hh[400 + j];
        b1v = b1[j];
    }
    float bmuv = 0.f, bvav = 0.f;
    if (w < 4) {
        const int jm = (w & 1) * 16 + col;
        if (jm < 30) { bmuv = bmu[jm]; bvav = bvar[jm]; }
    }

    // ---- init: zero LDS (pad slots must be 0), load h0/s0/a0 ----
    for (int i = tid; i < 2 * 7 * 512;     i += THREADS) Xb[i] = 0;
    for (int i = tid; i < 2 * 2 * 7 * 512; i += THREADS) Hb[i] = 0;
    for (int i = tid; i < 2 * 7 * 512;     i += THREADS) HIDb[i] = 0;
    for (int i = tid; i < 2 * 2 * 512;     i += THREADS) SAb[i] = 0;
    __syncthreads();
    for (int i = tid; i < ROWS * 200; i += THREADS) {
        int r = i / 200, jj = i % 200;
        Hb[((0 * 2 + (r >> 4)) * 7 + (jj >> 5)) * 512 + fragSlot(r & 15, jj)] =
            f2b(h0[(size_t)(brow0 + r) * 200 + jj]);
    }
    for (int i = tid; i < ROWS * 30; i += THREADS) {
        int r = i / 30, jj = i % 30;
        SAb[((r >> 4) * 2) * 512 + fragSlot(r & 15, jj)] =
            f2b(s0[(size_t)(brow0 + r) * 30 + jj]);
    }
    for (int i = tid; i < ROWS * 6; i += THREADS) {
        int r = i / 6, c = i % 6, k = 30 + c;
        SAb[((r >> 4) * 2 + (k >> 5)) * 512 + fragSlot(r & 15, k)] =
            f2b(ld_nt(&actions[(size_t)(brow0 + r) * 6 + c]));
    }
    __syncthreads();

    for (int t = 0; t < T_STEPS; ++t) {
        const int cur = t & 1, nxt = cur ^ 1;

        // ---------- Phase 1: x = FC(concat(s,a)) -> Xb ----------
        {
            f32x4 c0 = {0.f,0.f,0.f,0.f}, c1 = {0.f,0.f,0.f,0.f};
            #pragma unroll
            for (int ks = 0; ks < 2; ++ks) {
                bf16x8 a0 = *reinterpret_cast<const bf16x8*>(&SAb[(0 * 2 + ks) * 512 + lane * 8]);
                bf16x8 a1 = *reinterpret_cast<const bf16x8*>(&SAb[(1 * 2 + ks) * 512 + lane * 8]);
                c0 = MFMA(a0, wFC[ks], c0);
                c1 = MFMA(a1, wFC[ks], c1);
            }
            if (jt < 14) {
                #pragma unroll
                for (int q = 0; q < 4; ++q) {
                    Xb[(0 * 7 + (j >> 5)) * 512 + fragSlot(kg * 4 + q, j)] = f2b(c0[q] + bfcv);
                    Xb[(1 * 7 + (j >> 5)) * 512 + fragSlot(kg * 4 + q, j)] = f2b(c1[q] + bfcv);
                }
            }
        }
        __syncthreads();

        // ---------- Phase 2: gate GEMMs + elementwise; h_new -> Hb[nxt] ----------
        {
            f32x4 aR[2], aZ[2], aNi[2], aNh[2];
            #pragma unroll
            for (int mt = 0; mt < 2; ++mt) {
                aR[mt] = (f32x4){0.f,0.f,0.f,0.f}; aZ[mt] = (f32x4){0.f,0.f,0.f,0.f};
                aNi[mt] = (f32x4){0.f,0.f,0.f,0.f}; aNh[mt] = (f32x4){0.f,0.f,0.f,0.f};
            }
            #pragma unroll
            for (int ks = 0; ks < 14; ++ks) {
                #pragma unroll
                for (int mt = 0; mt < 2; ++mt) {
                    bf16x8 a = (ks < 7)
                        ? *reinterpret_cast<const bf16x8*>(&Xb[(mt * 7 + ks) * 512 + lane * 8])
                        : *reinterpret_cast<const bf16x8*>(&Hb[((cur * 2 + mt) * 7 + (ks - 7)) * 512 + lane * 8]);
                    aR[mt] = MFMA(a, wR[ks], aR[mt]);
                    aZ[mt] = MFMA(a, wZ[ks], aZ[mt]);
                    if (ks < 7) aNi[mt] = MFMA(a, wN[ks], aNi[mt]);
                    else        aNh[mt] = MFMA(a, wN[ks], aNh[mt]);
                }
            }
            #pragma unroll
            for (int mt = 0; mt < 2; ++mt) {
                #pragma unroll
                for (int q = 0; q < 4; ++q) {
                    const int r0 = kg * 4 + q;
                    const int slot = (j >> 5) * 512 + fragSlot(r0, j);
                    float rg = sigmf(aR[mt][q] + brv);
                    float zg = sigmf(aZ[mt][q] + bzv);
                    float ng = tanh_fast((aNi[mt][q] + biv) + rg * (aNh[mt][q] + bhv));
                    if (jv) {
                        float hv = b2f(Hb[(cur * 2 + mt) * 7 * 512 + slot]);
                        float hn = (1.f - zg) * ng + zg * hv;
                        Hb[(nxt * 2 + mt) * 7 * 512 + slot] = f2b(hn);
                        STG_S[(mt * 16 + r0) * 200 + j] = hn;
                    }
                }
            }
        }
        __syncthreads();

        // ---------- Phase 3: hid = relu(h_new @ W1^T + b1) -> HIDb ----------
        {
            f32x4 c0 = {0.f,0.f,0.f,0.f}, c1 = {0.f,0.f,0.f,0.f};
            #pragma unroll
            for (int ks = 0; ks < 7; ++ks) {
                bf16x8 a0 = *reinterpret_cast<const bf16x8*>(&Hb[((nxt * 2 + 0) * 7 + ks) * 512 + lane * 8]);
                bf16x8 a1 = *reinterpret_cast<const bf16x8*>(&Hb[((nxt * 2 + 1) * 7 + ks) * 512 + lane * 8]);
                c0 = MFMA(a0, wW1[ks], c0);
                c1 = MFMA(a1, wW1[ks], c1);
            }
            if (jt < 14) {
                #pragma unroll
                for (int q = 0; q < 4; ++q) {
                    HIDb[(0 * 7 + (j >> 5)) * 512 + fragSlot(kg * 4 + q, j)] = f2b(fmaxf(c0[q] + b1v, 0.f));
                    HIDb[(1 * 7 + (j >> 5)) * 512 + fragSlot(kg * 4 + q, j)] = f2b(fmaxf(c1[q] + b1v, 0.f));
                }
            }
        }
        __syncthreads();

        // ---------- Phase 4: waves 0-3 mu/var -> s_new ; waves 4-15 drain + prefetch a ----------
        if (w < 4) {
            const int mt = w >> 1, ntile = w & 1;
            f32x4 cm = {0.f,0.f,0.f,0.f}, cv = {0.f,0.f,0.f,0.f};
            #pragma unroll
            for (int ks = 0; ks < 7; ++ks) {
                bf16x8 a = *reinterpret_cast<const bf16x8*>(&HIDb[(mt * 7 + ks) * 512 + lane * 8]);
                cm = MFMA(a, wM[ks], cm);
                cv = MFMA(a, wV[ks], cv);
            }
            const int jm = ntile * 16 + col;
            const bool jmv = (jm < 30);
            #pragma unroll
            for (int q = 0; q < 4; ++q) {
                const int r0 = kg * 4 + q;
                const int row = mt * 16 + r0;
                float mu = cm[q] + bmuv;
                float vr = cv[q] + bvav;
                float var = ((vr > 20.f) ? vr : log1pf(__expf(vr))) + 0.1f;
                if (jmv) {
                    float eps = ld_nt(&noise[((size_t)t * BATCH + brow0 + row) * 30 + jm]);
                    float sn = mu + var * eps;
                    STG_Z[t & 1][row * 30 + jm] = sn;
                    SAb[(mt * 2) * 512 + fragSlot(r0, jm)] = f2b(sn);
                }
            }
        } else {
            const int di = (w - 4) * 64 + lane;   // 0..767
            float* dst = out_states + ((size_t)t * BATCH + brow0) * 200;
            for (int i = di; i < 1600; i += 768) {
                f32x4 v = *reinterpret_cast<const f32x4*>(&STG_S[i * 4]);
                st_nt4(dst + i * 4, v);
            }
            if (t >= 1 && di < 240) {
                f32x4 v = *reinterpret_cast<const f32x4*>(&STG_Z[(t - 1) & 1][di * 4]);
                st_nt4(out_stoch + ((size_t)(t - 1) * BATCH + brow0) * 30 + di * 4, v);
            }
            if (t + 1 < T_STEPS && di < ROWS * 6) {
                const int r = di / 6, c = di % 6, k = 30 + c;
                float av = ld_nt(&actions[((size_t)(t + 1) * BATCH + brow0 + r) * 6 + c]);
                SAb[((r >> 4) * 2 + (k >> 5)) * 512 + fragSlot(r & 15, k)] = f2b(av);
            }
        }
        __syncthreads();
    }

    // drain stoch(T-1)
    if (tid < 240) {
        f32x4 v = *reinterpret_cast<const f32x4*>(&STG_Z[(T_STEPS - 1) & 1][tid * 4]);
        st_nt4(out_stoch + ((size_t)(T_STEPS - 1) * BATCH + brow0) * 30 + tid * 4, v);
    }
}

extern "C" void kernel_launch(void* const* d_in, const int* in_sizes, int n_in,
                              void* d_out, int out_size, void* d_ws, size_t ws_size,
                              hipStream_t stream)
{
    const float* actions = (const float*)d_in[0];
    const float* h0      = (const float*)d_in[1];
    const float* s0      = (const float*)d_in[2];
    const float* noise   = (const float*)d_in[3];
    const float* Wfc     = (const float*)d_in[4];
    const float* bfc     = (const float*)d_in[5];
    const float* Wih     = (const float*)d_in[6];
    const float* bih     = (const float*)d_in[7];
    const float* Whh     = (const float*)d_in[8];
    const float* bhh     = (const float*)d_in[9];
    const float* W1      = (const float*)d_in[10];
    const float* b1      = (const float*)d_in[11];
    const float* Wmu     = (const float*)d_in[12];
    const float* bmu     = (const float*)d_in[13];
    const float* Wvar    = (const float*)d_in[14];
    const float* bvar    = (const float*)d_in[15];

    unsigned short* wbuf = (unsigned short*)d_ws;

    rssm_prep<<<(W_TOTAL + 255) / 256, 256, 0, stream>>>(Wfc, Wih, Whh, W1, Wmu, Wvar, wbuf);
    rssm_main<<<NBLK, THREADS, 0, stream>>>(actions, h0, s0, noise, bfc, bih, bhh, b1,
                                            bmu, bvar, wbuf, (float*)d_out);
}